// Round 1
// 230.823 us; speedup vs baseline: 1.0073x; 1.0073x over previous
//
#include <hip/hip_runtime.h>

#define NN 20000
#define EE 320000
#define CAP 64           // slab slots per node (in-degree ~ Poisson(16))
#define SVC 72           // per-wave edge capacity (CAP + ovf slack + self)
#define OVCAP 8192
#define EBLK 313         // edge blocks: ceil(320000/1024)

// consts layout (float offsets)
#define WZ_O 0
#define BZ_O 512
#define WH_O 576
#define BH_O 1088
#define OWT_O 1152       // transposed+padded out weights: [p][68] (k<64 valid)
#define OB_O 1968
#define PR_O 1980
#define NCONST 1992

#define LOG2E 1.44269504088896340736f

__device__ __forceinline__ float b2f(unsigned short h) {
  union { unsigned int u; float f; } v; v.u = ((unsigned int)h) << 16; return v.f;
}
__device__ __forceinline__ unsigned short f2b(float f) {
  union { unsigned int u; float f; } v; v.f = f;
  unsigned int u = v.u;
  unsigned int r = (u + 0x7fffu + ((u >> 16) & 1u)) >> 16;  // RNE
  return (unsigned short)r;
}
__device__ __forceinline__ float ldw(const void* p, int i, int isbf) {
  return isbf ? b2f(((const unsigned short*)p)[i]) : ((const float*)p)[i];
}
__device__ __forceinline__ void upk(unsigned int w, float& x0, float& x1) {
  union { unsigned int u; float f; } lo, hi;
  lo.u = w << 16; hi.u = w & 0xffff0000u;
  x0 = lo.f; x1 = hi.f;
}
__device__ __forceinline__ float degf(unsigned long long dc) {
  return (float)(unsigned int)dc * (1.0f / 1048576.0f);
}
__device__ __forceinline__ float ex2(float x) {
#if __has_builtin(__builtin_amdgcn_exp2f)
  return __builtin_amdgcn_exp2f(x);
#else
  return __exp2f(x);
#endif
}

struct __align__(4) U3 { unsigned int x, y, z; };   // 12B, 4B-aligned (dwordx3)

// 1) k_append: blocks 0..EBLK-1 process 4 edges/thread (one packed 64-bit atomic
//    per edge -> slot index in hi32 + fixed-point weighted degree in lo32; degcnt
//    pre-zeroed by a 160 KB memset). Block EBLK (concurrent): fused-weight prep.
//    Gate weights are pre-scaled by log2(e) (z) / 2*log2(e) (h) so k_node uses
//    bare v_exp_f32 (exp2) with no per-element multiplies.
__global__ void __launch_bounds__(256) k_append(
    const void* __restrict__ ei, const void* __restrict__ ea,
    unsigned long long* __restrict__ degcnt,
    unsigned int* __restrict__ slab,
    int* __restrict__ ovf_cnt, int* __restrict__ ovf_dst,
    unsigned int* __restrict__ ovf_pack, float* __restrict__ consts,
    const void* czw, const void* czb, const void* chw, const void* chb,
    const void* lzw, const void* lzb, const void* lhw, const void* lhb,
    const void* att, const void* ow, const void* ob) {
  __shared__ int sfl[2];
  const int tid = threadIdx.x;
  if (tid < 64) {
    // edge_attr in (0,1): packed-bf16 words have sign bits 15/31==0; f32 random bit15
    unsigned long long b1 = __ballot((((const unsigned int*)ea)[tid] >> 15) & 1u);
    // edge_index < 20000: int64 arrays have all odd 32-bit words == 0
    unsigned long long b2 = __ballot(((const unsigned int*)ei)[2 * tid + 1] != 0u);
    if (tid == 0) {
      sfl[0] = (b1 == 0ull) ? 1 : 0;   // 1 = floats are bf16
      sfl[1] = (b2 == 0ull) ? 1 : 0;   // 1 = indices are int64
    }
  }
  __syncthreads();
  const int isbf = sfl[0], is64 = sfl[1];

  if (blockIdx.x == EBLK) {
    // ---- weight prep block (concurrent with edge blocks) ----
    for (int idx = tid; idx < 512; idx += 256) {
      int f = idx >> 6, k = idx & 63;
      float sz = 0.f, sh = 0.f;
      for (int h = 0; h < 64; ++h) {
        sz += ldw(czw, f * 64 + h, isbf) * ldw(lzw, h * 64 + k, isbf);
        sh += ldw(chw, f * 64 + h, isbf) * ldw(lhw, h * 64 + k, isbf);
      }
      consts[WZ_O + idx] = sz * LOG2E;
      consts[WH_O + idx] = sh * (2.0f * LOG2E);
    }
    for (int idx = tid; idx < 64; idx += 256) {
      float sz = ldw(lzb, idx, isbf), sh = ldw(lhb, idx, isbf);
      for (int h = 0; h < 64; ++h) {
        sz += ldw(czb, h, isbf) * ldw(lzw, h * 64 + idx, isbf);
        sh += ldw(chb, h, isbf) * ldw(lhw, h * 64 + idx, isbf);
      }
      consts[BZ_O + idx] = sz * LOG2E;
      consts[BH_O + idx] = sh * (2.0f * LOG2E);
    }
    for (int idx = tid; idx < 816; idx += 256) {    // out weights [p][k], rows padded to 68
      int p = idx / 68, kk = idx % 68;
      consts[OWT_O + idx] = (kk < 64) ? ldw(ow, kk * 12 + p, isbf) : 0.f;
    }
    if (tid < 12) consts[OB_O + tid] = ldw(ob, tid, isbf);
    if (tid == 0) {
      float a[12]; float m = -1e30f;
      for (int p = 0; p < 12; ++p) { a[p] = ldw(att, p, isbf); m = fmaxf(m, a[p]); }
      float ssum = 0.f;
      for (int p = 0; p < 12; ++p) { a[p] = __expf(a[p] - m); ssum += a[p]; }
      for (int p = 0; p < 12; ++p) consts[PR_O + p] = a[p] / ssum;
    }
    return;
  }

  // ---- edge blocks: 4 edges per thread, independent chains ----
  const int e0 = blockIdx.x * 1024 + tid;
#pragma unroll
  for (int u = 0; u < 4; ++u) {
    int e = e0 + 256 * u;
    if (e >= EE) continue;
    int r, c;
    if (is64) {
      r = (int)((const unsigned int*)ei)[2 * e];
      c = (int)((const unsigned int*)ei)[2 * (EE + e)];
    } else {
      r = ((const int*)ei)[e];
      c = ((const int*)ei)[EE + e];
    }
    unsigned short wb;
    float w;
    if (isbf) { wb = ((const unsigned short*)ea)[e]; w = b2f(wb); }
    else      { w = ((const float*)ea)[e]; wb = f2b(w); }
    unsigned long long pk = (1ull << 32) |
        (unsigned long long)(unsigned int)__float2int_rn(w * 1048576.0f);
    unsigned long long old = atomicAdd(&degcnt[c], pk);
    int pos = (int)(old >> 32);
    unsigned int packed = ((unsigned int)wb << 16) | (unsigned int)r;
    if (pos < CAP) {
      slab[c * CAP + pos] = packed;
    } else {
      int oi = atomicAdd(ovf_cnt, 1);
      if (oi < OVCAP) { ovf_dst[oi] = c; ovf_pack[oi] = packed; }
    }
  }
}

#define ACC6(u, v)                                           \
  { float x0, x1;                                            \
    upk((u).x, x0, x1); a[0] += (v) * x0; a[1] += (v) * x1;  \
    upk((u).y, x0, x1); a[2] += (v) * x0; a[3] += (v) * x1;  \
    upk((u).z, x0, x1); a[4] += (v) * x0; a[5] += (v) * x1; }

#define ACCF6(f0, f1, f2, v)                                                   \
  { a[0] += (v) * (f0).x; a[1] += (v) * (f0).y; a[2] += (v) * (f1).x;          \
    a[3] += (v) * (f1).y; a[4] += (v) * (f2).x; a[5] += (v) * (f2).y; }

// 2) barrier-free wave-per-node: 4 waves/block, each wave owns one node.
//    Gather: ALL 64 lanes, 6 payload elems each (dwordx3) -> divmod-free
//    scatter (6*16 == 96 == 8*12 so p never wraps). dn folded into staged v.
__global__ void __launch_bounds__(256) k_node(
    const void* __restrict__ x, const void* __restrict__ ea,
    const unsigned long long* __restrict__ degcnt,
    const unsigned int* __restrict__ slab,
    const int* __restrict__ ovf_cnt, const int* __restrict__ ovf_dst,
    const unsigned int* __restrict__ ovf_pack,
    const float* __restrict__ consts,
    void* __restrict__ out) {
  __shared__ __align__(16) float sow[840];        // owT 816 | ob 12 | pr 12
  __shared__ __align__(16) int2  sv[4 * SVC];     // per-wave edges {elem-off, v-bits}
  __shared__ __align__(16) float accT[4 * 384];   // per-wave [b][p][f]
  __shared__ __align__(16) float hw[4 * 272];     // per-wave [b][68]
  __shared__ int swcnt[4];
  __shared__ int sfl[1];

  const int tid  = threadIdx.x;
  const int w    = tid >> 6;
  const int lane = tid & 63;
  const int n    = blockIdx.x * 4 + w;

  if (tid < 64) {
    unsigned long long b1 = __ballot((((const unsigned int*)ea)[tid] >> 15) & 1u);
    if (tid == 0) sfl[0] = (b1 == 0ull) ? 1 : 0;
  }
  for (int i = tid; i < 840; i += 256) sow[i] = consts[OWT_O + i];
  float wz[8], wh[8];
#pragma unroll
  for (int f = 0; f < 8; ++f) {
    wz[f] = consts[WZ_O + f * 64 + lane];
    wh[f] = consts[WH_O + f * 64 + lane];
  }
  const float bz = consts[BZ_O + lane], bh = consts[BH_O + lane];
  __syncthreads();   // sow + sfl ready (only block barrier)
  const int isbf = sfl[0];

  // --- stage this wave's edges into its LDS slab (v includes dest-side dn) ---
  unsigned long long dcn = degcnt[n];
  int cnt = (int)(dcn >> 32);
  int base = cnt < CAP ? cnt : CAP;
  const float dn = rsqrtf(degf(dcn) + 1.0f);
  int2* svw = &sv[w * SVC];
  if (lane == 0) swcnt[w] = base;
  if (lane < base) {
    unsigned int pk = slab[n * CAP + lane];
    int s = (int)(pk & 0xffffu);
    float v = b2f((unsigned short)(pk >> 16)) * rsqrtf(degf(degcnt[s]) + 1.0f) * dn;
    svw[lane] = make_int2(s * 96, __float_as_int(v));
  }
  int m0 = base;
  {
    int ov = ovf_cnt[0];                 // expected 0
    if (ov > 0) {
      if (ov > OVCAP) ov = OVCAP;
      for (int i = lane; i < ov; i += 64) {
        if (ovf_dst[i] == n) {
          int idx = atomicAdd(&swcnt[w], 1);
          if (idx < SVC - 1) {
            unsigned int pk = ovf_pack[i];
            int s = (int)(pk & 0xffffu);
            float v = b2f((unsigned short)(pk >> 16)) *
                      rsqrtf(degf(degcnt[s]) + 1.0f) * dn;
            svw[idx] = make_int2(s * 96, __float_as_int(v));
          }
        }
      }
      __builtin_amdgcn_wave_barrier();
      m0 = swcnt[w];
      if (m0 > SVC - 1) m0 = SVC - 1;
    }
  }
  if (lane == 0) svw[m0] = make_int2(n * 96, __float_as_int(dn * dn));  // self loop
  const int m1 = m0 + 1;
  __builtin_amdgcn_wave_barrier();

  // --- gather: all 64 lanes, lane owns 6 payload elems; 2-wide pipelined loads ---
  float a[6];
#pragma unroll
  for (int t = 0; t < 6; ++t) a[t] = 0.f;
  {
    const int i15 = lane & 15;
    const long xbase = (long)(lane >> 4) * (NN * 96) + 6 * i15;
    if (isbf) {
      const unsigned short* xr = (const unsigned short*)x + xbase;
      int j = 0;
      for (; j + 1 < m1; j += 2) {
        int2 e0 = svw[j], e1 = svw[j + 1];
        U3 u0 = *(const U3*)(xr + e0.x);
        U3 u1 = *(const U3*)(xr + e1.x);
        float v0 = __int_as_float(e0.y), v1 = __int_as_float(e1.y);
        ACC6(u0, v0); ACC6(u1, v1);
      }
      if (j < m1) {
        int2 e0 = svw[j];
        U3 u0 = *(const U3*)(xr + e0.x);
        float v0 = __int_as_float(e0.y);
        ACC6(u0, v0);
      }
    } else {
      const float* xf = (const float*)x + xbase;
      int j = 0;
      for (; j + 1 < m1; j += 2) {
        int2 e0 = svw[j], e1 = svw[j + 1];
        const float2* p0 = (const float2*)(xf + e0.x);
        const float2* p1 = (const float2*)(xf + e1.x);
        float2 u00 = p0[0], u01 = p0[1], u02 = p0[2];
        float2 u10 = p1[0], u11 = p1[1], u12 = p1[2];
        float v0 = __int_as_float(e0.y), v1 = __int_as_float(e1.y);
        ACCF6(u00, u01, u02, v0); ACCF6(u10, u11, u12, v1);
      }
      if (j < m1) {
        int2 e0 = svw[j];
        const float2* p0 = (const float2*)(xf + e0.x);
        float2 u00 = p0[0], u01 = p0[1], u02 = p0[2];
        float v0 = __int_as_float(e0.y);
        ACCF6(u00, u01, u02, v0);
      }
    }
    // divmod-free scatter-transpose into accT[b][p][f]:
    // oc = 6*i15 -> f = i15>>1 (fixed), p = 6*(i15&1)+t (t<6, never wraps)
    float* aw = &accT[w * 384 + (lane >> 4) * 96 + (i15 & 1) * 48 + (i15 >> 1)];
#pragma unroll
    for (int t = 0; t < 6; ++t) aw[8 * t] = a[t];
  }
  __builtin_amdgcn_wave_barrier();

  // --- gates: lane = hidden index k; weights pre-scaled by log2e -> bare exp2 ---
  {
    const float* accTw = &accT[w * 384];
    float* hww = &hw[w * 272];
    float prv[12];
#pragma unroll
    for (int p = 0; p < 12; ++p) prv[p] = sow[828 + p];
#pragma unroll
    for (int b = 0; b < 4; ++b) {
      float hbl = 0.f;
#pragma unroll
      for (int p = 0; p < 12; ++p) {
        const float4* A = (const float4*)&accTw[b * 96 + p * 8];
        float4 A0 = A[0], A1 = A[1];
        float za = bz + A0.x * wz[0] + A0.y * wz[1] + A0.z * wz[2] + A0.w * wz[3]
                      + A1.x * wz[4] + A1.y * wz[5] + A1.z * wz[6] + A1.w * wz[7];
        float ta = bh + A0.x * wh[0] + A0.y * wh[1] + A0.z * wh[2] + A0.w * wh[3]
                      + A1.x * wh[4] + A1.y * wh[5] + A1.z * wh[6] + A1.w * wh[7];
        // (1 - sigmoid(z)) * tanh(t) = (eh-1)/((1+ea)(1+eh)), ea=2^za, eh=2^ta
        float ea2 = ex2(za);
        float eh = ex2(fminf(ta, 115.0f));
        float num = eh - 1.0f;
        float den = (1.0f + ea2) * (1.0f + eh);
        hbl += prv[p] * (num * __builtin_amdgcn_rcpf(den));
      }
      hww[b * 68 + lane] = fmaxf(hbl, 0.f);   // relu
    }
  }
  __builtin_amdgcn_wave_barrier();

  // --- out projection: lane t<48 -> (b,p); vectorized b128 reads ---
  if (lane < 48) {
    const float* hww = &hw[w * 272];
    int b = lane / 12, p = lane % 12;
    float o = sow[816 + p];
#pragma unroll
    for (int kq = 0; kq < 16; ++kq) {
      float4 hv = *(const float4*)&hww[b * 68 + 4 * kq];
      float4 wv = *(const float4*)&sow[p * 68 + 4 * kq];
      o += hv.x * wv.x + hv.y * wv.y + hv.z * wv.z + hv.w * wv.w;
    }
    int oi = (b * NN + n) * 12 + p;
    if (isbf) ((unsigned short*)out)[oi] = f2b(o);
    else      ((float*)out)[oi] = o;
  }
}

extern "C" void kernel_launch(void* const* d_in, const int* in_sizes, int n_in,
                              void* d_out, int out_size, void* d_ws, size_t ws_size,
                              hipStream_t stream) {
  const void* x   = d_in[0];
  const void* ei  = d_in[1];
  const void* ea  = d_in[2];
  const void* czw = d_in[3];
  const void* czb = d_in[4];
  // d_in[5], d_in[6]: conv_r_* — dead (H0 = 0)
  const void* chw = d_in[7];
  const void* chb = d_in[8];
  const void* lzw = d_in[9];
  const void* lzb = d_in[10];
  // d_in[11], d_in[12]: lin_r_* — dead
  const void* lhw = d_in[13];
  const void* lhb = d_in[14];
  const void* att = d_in[15];
  const void* ow  = d_in[16];
  const void* ob  = d_in[17];

  // workspace ~5.4 MB
  char* ws = (char*)d_ws;
  float* consts  = (float*)(ws + 256);              // 1992 f32 -> ends 8224
  unsigned long long* degcnt = (unsigned long long*)(ws + 8448);   // 160,000 B compact
  int*   ovf_cnt = (int*)  (ws + 168448);           // right after degcnt (one memset)
  int*   ovf_dst = (int*)  (ws + 168704);           // 32768 B
  unsigned int* ovf_pack = (unsigned int*)(ws + 201472);  // 32768 B
  unsigned int* slab     = (unsigned int*)(ws + 234240);  // 5,120,000 B -> 5,354,240

  // zero degcnt + ovf_cnt (160 KB DMA fill)
  hipMemsetAsync(ws + 8448, 0, 160064, stream);
  k_append<<<dim3(EBLK + 1), dim3(256), 0, stream>>>(ei, ea, degcnt, slab,
                                                     ovf_cnt, ovf_dst, ovf_pack,
                                                     consts,
                                                     czw, czb, chw, chb,
                                                     lzw, lzb, lhw, lhb,
                                                     att, ow, ob);
  k_node<<<dim3(NN / 4), dim3(256), 0, stream>>>(x, ea, degcnt, slab,
                                                 ovf_cnt, ovf_dst, ovf_pack,
                                                 consts, d_out);
}

// Round 3
// 229.953 us; speedup vs baseline: 1.0111x; 1.0038x over previous
//
#include <hip/hip_runtime.h>
#include <hip/hip_cooperative_groups.h>

namespace cg = cooperative_groups;

#define NN 20000
#define EE 320000
#define CAP 64           // slab slots per node (in-degree ~ Poisson(16))
#define SVC 72           // per-wave edge capacity (CAP + ovf slack + self)
#define OVCAP 8192
#define EBLK 313         // fallback edge blocks: ceil(320000/1024)
#define GRID 1024        // fused grid: 4 blocks/CU x 256 CU (guaranteed by launch_bounds)
#define NWP 5            // weight-prep blocks in fused phase 1

// consts layout (float offsets)
#define WZ_O 0
#define BZ_O 512
#define WH_O 576
#define BH_O 1088
#define OWT_O 1152       // transposed+padded out weights: [p][68] (k<64 valid)
#define OB_O 1968
#define PR_O 1980

#define LOG2E 1.44269504088896340736f

typedef float v2f __attribute__((ext_vector_type(2)));

__device__ __forceinline__ v2f mk2(float a, float b) { v2f t; t.x = a; t.y = b; return t; }
__device__ __forceinline__ v2f pkfma(v2f a, v2f b, v2f c) {
  v2f d;
  asm("v_pk_fma_f32 %0, %1, %2, %3" : "=v"(d) : "v"(a), "v"(b), "v"(c));
  return d;
}
__device__ __forceinline__ v2f pkmul(v2f a, v2f b) {
  v2f d;
  asm("v_pk_mul_f32 %0, %1, %2" : "=v"(d) : "v"(a), "v"(b));
  return d;
}

__device__ __forceinline__ float b2f(unsigned short h) {
  union { unsigned int u; float f; } v; v.u = ((unsigned int)h) << 16; return v.f;
}
__device__ __forceinline__ unsigned short f2b(float f) {
  union { unsigned int u; float f; } v; v.f = f;
  unsigned int u = v.u;
  unsigned int r = (u + 0x7fffu + ((u >> 16) & 1u)) >> 16;  // RNE
  return (unsigned short)r;
}
__device__ __forceinline__ float ldw(const void* p, int i, int isbf) {
  return isbf ? b2f(((const unsigned short*)p)[i]) : ((const float*)p)[i];
}
__device__ __forceinline__ void upk(unsigned int w, float& x0, float& x1) {
  union { unsigned int u; float f; } lo, hi;
  lo.u = w << 16; hi.u = w & 0xffff0000u;
  x0 = lo.f; x1 = hi.f;
}
__device__ __forceinline__ float degf(unsigned long long dc) {
  return (float)(unsigned int)dc * (1.0f / 1048576.0f);
}
__device__ __forceinline__ float ex2(float x) {
#if __has_builtin(__builtin_amdgcn_exp2f)
  return __builtin_amdgcn_exp2f(x);
#else
  return __exp2f(x);
#endif
}
__device__ __forceinline__ v2f bpk(unsigned int u) {   // packed bf16 word -> 2 floats
  union { unsigned int i; float f; } lo, hi;
  lo.i = u << 16; hi.i = u & 0xffff0000u;
  return mk2(lo.f, hi.f);
}

struct __align__(4) U3 { unsigned int x, y, z; };   // 12B dwordx3 load

#define ACC6P(u, vv)                              \
  { aa0 = pkfma(bpk((u).x), vv, aa0);             \
    aa1 = pkfma(bpk((u).y), vv, aa1);             \
    aa2 = pkfma(bpk((u).z), vv, aa2); }

// ===================== fused persistent kernel (cooperative) =====================
// phase 1: edge append (blocks 0..GRID-NWP-1, grid-stride) + weight prep
//          (last NWP blocks, sliced).  grid.sync().
// phase 2: wave-per-node pipeline, nodes pulled from an atomic work queue.
__global__ void __launch_bounds__(256, 4) k_fused(
    const void* __restrict__ x, const void* __restrict__ ei,
    const void* __restrict__ ea,
    const void* czw, const void* czb, const void* chw, const void* chb,
    const void* lzw, const void* lzb, const void* lhw, const void* lhb,
    const void* att, const void* ow, const void* ob,
    unsigned long long* __restrict__ degcnt,
    unsigned int* __restrict__ slab,
    int* __restrict__ ovf_cnt, int* __restrict__ ovf_dst,
    unsigned int* __restrict__ ovf_pack,
    float* __restrict__ consts,
    int* __restrict__ wq,
    void* __restrict__ out) {
  __shared__ __align__(16) float sow[840];        // owT 816 | ob 12 | pr 12
  __shared__ __align__(16) int2  sv[4 * SVC];     // per-wave edges {elem-off, v-bits}
  __shared__ __align__(16) float accT[4 * 384];   // per-wave [b][p][f]
  __shared__ __align__(16) float hw[4 * 272];     // per-wave [b][68]
  __shared__ int swcnt[4];
  __shared__ int sfl[2];

  const int tid = threadIdx.x;
  const int bid = blockIdx.x;
  const int gsz = gridDim.x;

  if (tid < 64) {
    // edge_attr in (0,1): packed-bf16 words have sign bits 15/31==0; f32 random bit15
    unsigned long long b1 = __ballot((((const unsigned int*)ea)[tid] >> 15) & 1u);
    // edge_index < 20000: int64 arrays have all odd 32-bit words == 0
    unsigned long long b2 = __ballot(((const unsigned int*)ei)[2 * tid + 1] != 0u);
    if (tid == 0) {
      sfl[0] = (b1 == 0ull) ? 1 : 0;   // floats are bf16
      sfl[1] = (b2 == 0ull) ? 1 : 0;   // indices are int64
    }
  }
  __syncthreads();
  const int isbf = sfl[0], is64 = sfl[1];

  const int ebn = gsz - NWP;           // edge-append blocks
  if (bid < ebn) {
    // ---- phase 1a: edge append (degcnt/ovf_cnt zeroed by host memset) ----
    for (int e = bid * 256 + tid; e < EE; e += ebn * 256) {
      int r, c;
      if (is64) {
        r = (int)((const unsigned int*)ei)[2 * e];
        c = (int)((const unsigned int*)ei)[2 * (EE + e)];
      } else {
        r = ((const int*)ei)[e];
        c = ((const int*)ei)[EE + e];
      }
      unsigned short wb;
      float wv;
      if (isbf) { wb = ((const unsigned short*)ea)[e]; wv = b2f(wb); }
      else      { wv = ((const float*)ea)[e]; wb = f2b(wv); }
      unsigned long long pk = (1ull << 32) |
          (unsigned long long)(unsigned int)__float2int_rn(wv * 1048576.0f);
      unsigned long long old = atomicAdd(&degcnt[c], pk);
      int pos = (int)(old >> 32);
      unsigned int packed = ((unsigned int)wb << 16) | (unsigned int)r;
      if (pos < CAP) {
        slab[c * CAP + pos] = packed;
      } else {
        int oi = atomicAdd(ovf_cnt, 1);
        if (oi < OVCAP) { ovf_dst[oi] = c; ovf_pack[oi] = packed; }
      }
    }
  } else {
    // ---- phase 1b: weight prep, sliced across NWP blocks ----
    int role = bid - ebn;              // 0..NWP-1
    if (role < 4) {                    // WZ/WH quarter each (128 idx)
      for (int idx = role * 128 + tid; idx < (role + 1) * 128; idx += 256) {
        int f = idx >> 6, k = idx & 63;
        float sz = 0.f, sh = 0.f;
        for (int h = 0; h < 64; ++h) {
          sz += ldw(czw, f * 64 + h, isbf) * ldw(lzw, h * 64 + k, isbf);
          sh += ldw(chw, f * 64 + h, isbf) * ldw(lhw, h * 64 + k, isbf);
        }
        consts[WZ_O + idx] = sz * LOG2E;
        consts[WH_O + idx] = sh * (2.0f * LOG2E);
      }
    } else {                           // biases + out weights + attention
      for (int idx = tid; idx < 64; idx += 256) {
        float sz = ldw(lzb, idx, isbf), sh = ldw(lhb, idx, isbf);
        for (int h = 0; h < 64; ++h) {
          sz += ldw(czb, h, isbf) * ldw(lzw, h * 64 + idx, isbf);
          sh += ldw(chb, h, isbf) * ldw(lhw, h * 64 + idx, isbf);
        }
        consts[BZ_O + idx] = sz * LOG2E;
        consts[BH_O + idx] = sh * (2.0f * LOG2E);
      }
      for (int idx = tid; idx < 816; idx += 256) {  // out weights [p][k], rows padded to 68
        int p = idx / 68, kk = idx % 68;
        consts[OWT_O + idx] = (kk < 64) ? ldw(ow, kk * 12 + p, isbf) : 0.f;
      }
      if (tid < 12) consts[OB_O + tid] = ldw(ob, tid, isbf);
      if (tid == 0) {
        float a[12]; float m = -1e30f;
        for (int p = 0; p < 12; ++p) { a[p] = ldw(att, p, isbf); m = fmaxf(m, a[p]); }
        float ssum = 0.f;
        for (int p = 0; p < 12; ++p) { a[p] = __expf(a[p] - m); ssum += a[p]; }
        for (int p = 0; p < 12; ++p) consts[PR_O + p] = a[p] / ssum;
      }
    }
  }

  cg::this_grid().sync();

  // ---- phase 2: wave-per-node, atomic work queue ----
  const int w    = tid >> 6;
  const int lane = tid & 63;

  for (int i = tid; i < 840; i += 256) sow[i] = consts[OWT_O + i];
  v2f wzp[4], whp[4];
#pragma unroll
  for (int j = 0; j < 4; ++j) {
    wzp[j] = mk2(consts[WZ_O + (2 * j) * 64 + lane], consts[WZ_O + (2 * j + 1) * 64 + lane]);
    whp[j] = mk2(consts[WH_O + (2 * j) * 64 + lane], consts[WH_O + (2 * j + 1) * 64 + lane]);
  }
  const float bz = consts[BZ_O + lane], bh = consts[BH_O + lane];
  float prv[12];
#pragma unroll
  for (int p = 0; p < 12; ++p) prv[p] = consts[PR_O + p];
  __syncthreads();   // sow ready

  int ovt = ovf_cnt[0];              // expected 0; constant after grid sync
  if (ovt > OVCAP) ovt = OVCAP;

  for (;;) {
    int n;
    if (lane == 0) n = atomicAdd(wq, 1);
    n = __shfl(n, 0);
    if (n >= NN) break;

    // --- stage this wave's edges into its LDS slab (dest-side dn folded into v) ---
    unsigned long long dcn = degcnt[n];
    int cnt = (int)(dcn >> 32);
    int base = cnt < CAP ? cnt : CAP;
    const float dn = rsqrtf(degf(dcn) + 1.0f);
    int2* svw = &sv[w * SVC];
    if (lane == 0) swcnt[w] = base;
    if (lane < base) {
      unsigned int pk = slab[n * CAP + lane];
      int s = (int)(pk & 0xffffu);
      float v = b2f((unsigned short)(pk >> 16)) * rsqrtf(degf(degcnt[s]) + 1.0f) * dn;
      svw[lane] = make_int2(s * 96, __float_as_int(v));
    }
    int m0 = base;
    if (ovt > 0) {
      for (int i = lane; i < ovt; i += 64) {
        if (ovf_dst[i] == n) {
          int idx = atomicAdd(&swcnt[w], 1);
          if (idx < SVC - 1) {
            unsigned int pk = ovf_pack[i];
            int s = (int)(pk & 0xffffu);
            float v = b2f((unsigned short)(pk >> 16)) *
                      rsqrtf(degf(degcnt[s]) + 1.0f) * dn;
            svw[idx] = make_int2(s * 96, __float_as_int(v));
          }
        }
      }
      __builtin_amdgcn_wave_barrier();
      m0 = swcnt[w];
      if (m0 > SVC - 1) m0 = SVC - 1;
    }
    if (lane == 0) svw[m0] = make_int2(n * 96, __float_as_int(dn * dn));  // self loop
    const int m1 = m0 + 1;
    __builtin_amdgcn_wave_barrier();

    // --- gather: all 64 lanes, lane owns 6 payload elems; packed-f32 FMAs ---
    v2f aa0 = mk2(0.f, 0.f), aa1 = mk2(0.f, 0.f), aa2 = mk2(0.f, 0.f);
    const int i15 = lane & 15;
    const long xbase = (long)(lane >> 4) * (NN * 96) + 6 * i15;
    if (isbf) {
      const unsigned short* xr = (const unsigned short*)x + xbase;
      int j = 0;
      for (; j + 1 < m1; j += 2) {
        int2 e0 = svw[j], e1 = svw[j + 1];
        U3 u0 = *(const U3*)(xr + e0.x);
        U3 u1 = *(const U3*)(xr + e1.x);
        v2f vv0 = mk2(__int_as_float(e0.y), __int_as_float(e0.y));
        v2f vv1 = mk2(__int_as_float(e1.y), __int_as_float(e1.y));
        ACC6P(u0, vv0); ACC6P(u1, vv1);
      }
      if (j < m1) {
        int2 e0 = svw[j];
        U3 u0 = *(const U3*)(xr + e0.x);
        v2f vv0 = mk2(__int_as_float(e0.y), __int_as_float(e0.y));
        ACC6P(u0, vv0);
      }
    } else {
      const float* xf = (const float*)x + xbase;
      int j = 0;
      for (; j + 1 < m1; j += 2) {
        int2 e0 = svw[j], e1 = svw[j + 1];
        const v2f* p0 = (const v2f*)(xf + e0.x);
        const v2f* p1 = (const v2f*)(xf + e1.x);
        v2f u00 = p0[0], u01 = p0[1], u02 = p0[2];
        v2f u10 = p1[0], u11 = p1[1], u12 = p1[2];
        v2f vv0 = mk2(__int_as_float(e0.y), __int_as_float(e0.y));
        v2f vv1 = mk2(__int_as_float(e1.y), __int_as_float(e1.y));
        aa0 = pkfma(u00, vv0, aa0); aa1 = pkfma(u01, vv0, aa1); aa2 = pkfma(u02, vv0, aa2);
        aa0 = pkfma(u10, vv1, aa0); aa1 = pkfma(u11, vv1, aa1); aa2 = pkfma(u12, vv1, aa2);
      }
      if (j < m1) {
        int2 e0 = svw[j];
        const v2f* p0 = (const v2f*)(xf + e0.x);
        v2f vv0 = mk2(__int_as_float(e0.y), __int_as_float(e0.y));
        aa0 = pkfma(p0[0], vv0, aa0); aa1 = pkfma(p0[1], vv0, aa1); aa2 = pkfma(p0[2], vv0, aa2);
      }
    }
    // divmod-free scatter-transpose into accT[b][p][f]:
    // oc = 6*i15 -> f = i15>>1 (fixed), p = 6*(i15&1)+t (t<6, never wraps)
    {
      float* aw = &accT[w * 384 + (lane >> 4) * 96 + (i15 & 1) * 48 + (i15 >> 1)];
      aw[0]  = aa0.x; aw[8]  = aa0.y;
      aw[16] = aa1.x; aw[24] = aa1.y;
      aw[32] = aa2.x; aw[40] = aa2.y;
    }
    __builtin_amdgcn_wave_barrier();

    // --- gates: lane = hidden k; packed FMAs; weights pre-scaled by log2e -> bare exp2 ---
    {
      const float* accTw = &accT[w * 384];
      float* hww = &hw[w * 272];
#pragma unroll
      for (int b = 0; b < 4; ++b) {
        float hbl = 0.f;
#pragma unroll
        for (int p = 0; p < 12; ++p) {
          const float4* A = (const float4*)&accTw[b * 96 + p * 8];
          float4 A0 = A[0], A1 = A[1];
          v2f zv = pkmul(mk2(A0.x, A0.y), wzp[0]);
          zv = pkfma(mk2(A0.z, A0.w), wzp[1], zv);
          zv = pkfma(mk2(A1.x, A1.y), wzp[2], zv);
          zv = pkfma(mk2(A1.z, A1.w), wzp[3], zv);
          v2f tv = pkmul(mk2(A0.x, A0.y), whp[0]);
          tv = pkfma(mk2(A0.z, A0.w), whp[1], tv);
          tv = pkfma(mk2(A1.x, A1.y), whp[2], tv);
          tv = pkfma(mk2(A1.z, A1.w), whp[3], tv);
          float za = zv.x + zv.y + bz;
          float ta = tv.x + tv.y + bh;
          // (1 - sigmoid(z)) * tanh(t) = (eh-1)/((1+ea)(1+eh)), ea=2^za, eh=2^ta
          float ea2 = ex2(za);
          float eh = ex2(fminf(ta, 115.0f));
          float num = eh - 1.0f;
          float den = (1.0f + ea2) * (1.0f + eh);
          hbl += prv[p] * (num * __builtin_amdgcn_rcpf(den));
        }
        hww[b * 68 + lane] = fmaxf(hbl, 0.f);   // relu
      }
    }
    __builtin_amdgcn_wave_barrier();

    // --- out projection: lane t<48 -> (b,p); b128 reads + packed FMAs ---
    if (lane < 48) {
      const float* hww = &hw[w * 272];
      int b = lane / 12, p = lane % 12;
      v2f acc2 = mk2(0.f, 0.f);
#pragma unroll
      for (int kq = 0; kq < 16; ++kq) {
        float4 hv = *(const float4*)&hww[b * 68 + 4 * kq];
        float4 wv = *(const float4*)&sow[p * 68 + 4 * kq];
        acc2 = pkfma(mk2(hv.x, hv.y), mk2(wv.x, wv.y), acc2);
        acc2 = pkfma(mk2(hv.z, hv.w), mk2(wv.z, wv.w), acc2);
      }
      float o = acc2.x + acc2.y + sow[816 + p];
      int oi = (b * NN + n) * 12 + p;
      if (isbf) ((unsigned short*)out)[oi] = f2b(o);
      else      ((float*)out)[oi] = o;
    }
    __builtin_amdgcn_wave_barrier();
  }
}

// ===================== fallback path (verified R1 kernels, 230.8 µs) =====================
__global__ void __launch_bounds__(256) k_append(
    const void* __restrict__ ei, const void* __restrict__ ea,
    unsigned long long* __restrict__ degcnt,
    unsigned int* __restrict__ slab,
    int* __restrict__ ovf_cnt, int* __restrict__ ovf_dst,
    unsigned int* __restrict__ ovf_pack, float* __restrict__ consts,
    const void* czw, const void* czb, const void* chw, const void* chb,
    const void* lzw, const void* lzb, const void* lhw, const void* lhb,
    const void* att, const void* ow, const void* ob) {
  __shared__ int sfl[2];
  const int tid = threadIdx.x;
  if (tid < 64) {
    unsigned long long b1 = __ballot((((const unsigned int*)ea)[tid] >> 15) & 1u);
    unsigned long long b2 = __ballot(((const unsigned int*)ei)[2 * tid + 1] != 0u);
    if (tid == 0) {
      sfl[0] = (b1 == 0ull) ? 1 : 0;
      sfl[1] = (b2 == 0ull) ? 1 : 0;
    }
  }
  __syncthreads();
  const int isbf = sfl[0], is64 = sfl[1];

  if (blockIdx.x == EBLK) {
    for (int idx = tid; idx < 512; idx += 256) {
      int f = idx >> 6, k = idx & 63;
      float sz = 0.f, sh = 0.f;
      for (int h = 0; h < 64; ++h) {
        sz += ldw(czw, f * 64 + h, isbf) * ldw(lzw, h * 64 + k, isbf);
        sh += ldw(chw, f * 64 + h, isbf) * ldw(lhw, h * 64 + k, isbf);
      }
      consts[WZ_O + idx] = sz * LOG2E;
      consts[WH_O + idx] = sh * (2.0f * LOG2E);
    }
    for (int idx = tid; idx < 64; idx += 256) {
      float sz = ldw(lzb, idx, isbf), sh = ldw(lhb, idx, isbf);
      for (int h = 0; h < 64; ++h) {
        sz += ldw(czb, h, isbf) * ldw(lzw, h * 64 + idx, isbf);
        sh += ldw(chb, h, isbf) * ldw(lhw, h * 64 + idx, isbf);
      }
      consts[BZ_O + idx] = sz * LOG2E;
      consts[BH_O + idx] = sh * (2.0f * LOG2E);
    }
    for (int idx = tid; idx < 816; idx += 256) {
      int p = idx / 68, kk = idx % 68;
      consts[OWT_O + idx] = (kk < 64) ? ldw(ow, kk * 12 + p, isbf) : 0.f;
    }
    if (tid < 12) consts[OB_O + tid] = ldw(ob, tid, isbf);
    if (tid == 0) {
      float a[12]; float m = -1e30f;
      for (int p = 0; p < 12; ++p) { a[p] = ldw(att, p, isbf); m = fmaxf(m, a[p]); }
      float ssum = 0.f;
      for (int p = 0; p < 12; ++p) { a[p] = __expf(a[p] - m); ssum += a[p]; }
      for (int p = 0; p < 12; ++p) consts[PR_O + p] = a[p] / ssum;
    }
    return;
  }

  const int e0 = blockIdx.x * 1024 + tid;
#pragma unroll
  for (int u = 0; u < 4; ++u) {
    int e = e0 + 256 * u;
    if (e >= EE) continue;
    int r, c;
    if (is64) {
      r = (int)((const unsigned int*)ei)[2 * e];
      c = (int)((const unsigned int*)ei)[2 * (EE + e)];
    } else {
      r = ((const int*)ei)[e];
      c = ((const int*)ei)[EE + e];
    }
    unsigned short wb;
    float w;
    if (isbf) { wb = ((const unsigned short*)ea)[e]; w = b2f(wb); }
    else      { w = ((const float*)ea)[e]; wb = f2b(w); }
    unsigned long long pk = (1ull << 32) |
        (unsigned long long)(unsigned int)__float2int_rn(w * 1048576.0f);
    unsigned long long old = atomicAdd(&degcnt[c], pk);
    int pos = (int)(old >> 32);
    unsigned int packed = ((unsigned int)wb << 16) | (unsigned int)r;
    if (pos < CAP) {
      slab[c * CAP + pos] = packed;
    } else {
      int oi = atomicAdd(ovf_cnt, 1);
      if (oi < OVCAP) { ovf_dst[oi] = c; ovf_pack[oi] = packed; }
    }
  }
}

#define ACC6(u, v)                                           \
  { float x0, x1;                                            \
    upk((u).x, x0, x1); a[0] += (v) * x0; a[1] += (v) * x1;  \
    upk((u).y, x0, x1); a[2] += (v) * x0; a[3] += (v) * x1;  \
    upk((u).z, x0, x1); a[4] += (v) * x0; a[5] += (v) * x1; }

#define ACCF6(f0, f1, f2, v)                                                   \
  { a[0] += (v) * (f0).x; a[1] += (v) * (f0).y; a[2] += (v) * (f1).x;          \
    a[3] += (v) * (f1).y; a[4] += (v) * (f2).x; a[5] += (v) * (f2).y; }

__global__ void __launch_bounds__(256) k_node(
    const void* __restrict__ x, const void* __restrict__ ea,
    const unsigned long long* __restrict__ degcnt,
    const unsigned int* __restrict__ slab,
    const int* __restrict__ ovf_cnt, const int* __restrict__ ovf_dst,
    const unsigned int* __restrict__ ovf_pack,
    const float* __restrict__ consts,
    void* __restrict__ out) {
  __shared__ __align__(16) float sow[840];
  __shared__ __align__(16) int2  sv[4 * SVC];
  __shared__ __align__(16) float accT[4 * 384];
  __shared__ __align__(16) float hw[4 * 272];
  __shared__ int swcnt[4];
  __shared__ int sfl[1];

  const int tid  = threadIdx.x;
  const int w    = tid >> 6;
  const int lane = tid & 63;
  const int n    = blockIdx.x * 4 + w;

  if (tid < 64) {
    unsigned long long b1 = __ballot((((const unsigned int*)ea)[tid] >> 15) & 1u);
    if (tid == 0) sfl[0] = (b1 == 0ull) ? 1 : 0;
  }
  for (int i = tid; i < 840; i += 256) sow[i] = consts[OWT_O + i];
  float wz[8], wh[8];
#pragma unroll
  for (int f = 0; f < 8; ++f) {
    wz[f] = consts[WZ_O + f * 64 + lane];
    wh[f] = consts[WH_O + f * 64 + lane];
  }
  const float bz = consts[BZ_O + lane], bh = consts[BH_O + lane];
  __syncthreads();
  const int isbf = sfl[0];

  unsigned long long dcn = degcnt[n];
  int cnt = (int)(dcn >> 32);
  int base = cnt < CAP ? cnt : CAP;
  const float dn = rsqrtf(degf(dcn) + 1.0f);
  int2* svw = &sv[w * SVC];
  if (lane == 0) swcnt[w] = base;
  if (lane < base) {
    unsigned int pk = slab[n * CAP + lane];
    int s = (int)(pk & 0xffffu);
    float v = b2f((unsigned short)(pk >> 16)) * rsqrtf(degf(degcnt[s]) + 1.0f) * dn;
    svw[lane] = make_int2(s * 96, __float_as_int(v));
  }
  int m0 = base;
  {
    int ov = ovf_cnt[0];
    if (ov > 0) {
      if (ov > OVCAP) ov = OVCAP;
      for (int i = lane; i < ov; i += 64) {
        if (ovf_dst[i] == n) {
          int idx = atomicAdd(&swcnt[w], 1);
          if (idx < SVC - 1) {
            unsigned int pk = ovf_pack[i];
            int s = (int)(pk & 0xffffu);
            float v = b2f((unsigned short)(pk >> 16)) *
                      rsqrtf(degf(degcnt[s]) + 1.0f) * dn;
            svw[idx] = make_int2(s * 96, __float_as_int(v));
          }
        }
      }
      __builtin_amdgcn_wave_barrier();
      m0 = swcnt[w];
      if (m0 > SVC - 1) m0 = SVC - 1;
    }
  }
  if (lane == 0) svw[m0] = make_int2(n * 96, __float_as_int(dn * dn));
  const int m1 = m0 + 1;
  __builtin_amdgcn_wave_barrier();

  float a[6];
#pragma unroll
  for (int t = 0; t < 6; ++t) a[t] = 0.f;
  {
    const int i15 = lane & 15;
    const long xbase = (long)(lane >> 4) * (NN * 96) + 6 * i15;
    if (isbf) {
      const unsigned short* xr = (const unsigned short*)x + xbase;
      int j = 0;
      for (; j + 1 < m1; j += 2) {
        int2 e0 = svw[j], e1 = svw[j + 1];
        U3 u0 = *(const U3*)(xr + e0.x);
        U3 u1 = *(const U3*)(xr + e1.x);
        float v0 = __int_as_float(e0.y), v1 = __int_as_float(e1.y);
        ACC6(u0, v0); ACC6(u1, v1);
      }
      if (j < m1) {
        int2 e0 = svw[j];
        U3 u0 = *(const U3*)(xr + e0.x);
        float v0 = __int_as_float(e0.y);
        ACC6(u0, v0);
      }
    } else {
      const float* xf = (const float*)x + xbase;
      int j = 0;
      for (; j + 1 < m1; j += 2) {
        int2 e0 = svw[j], e1 = svw[j + 1];
        const float2* p0 = (const float2*)(xf + e0.x);
        const float2* p1 = (const float2*)(xf + e1.x);
        float2 u00 = p0[0], u01 = p0[1], u02 = p0[2];
        float2 u10 = p1[0], u11 = p1[1], u12 = p1[2];
        float v0 = __int_as_float(e0.y), v1 = __int_as_float(e1.y);
        ACCF6(u00, u01, u02, v0); ACCF6(u10, u11, u12, v1);
      }
      if (j < m1) {
        int2 e0 = svw[j];
        const float2* p0 = (const float2*)(xf + e0.x);
        float2 u00 = p0[0], u01 = p0[1], u02 = p0[2];
        float v0 = __int_as_float(e0.y);
        ACCF6(u00, u01, u02, v0);
      }
    }
    float* aw = &accT[w * 384 + (lane >> 4) * 96 + (i15 & 1) * 48 + (i15 >> 1)];
#pragma unroll
    for (int t = 0; t < 6; ++t) aw[8 * t] = a[t];
  }
  __builtin_amdgcn_wave_barrier();

  {
    const float* accTw = &accT[w * 384];
    float* hww = &hw[w * 272];
    float prv[12];
#pragma unroll
    for (int p = 0; p < 12; ++p) prv[p] = sow[828 + p];
#pragma unroll
    for (int b = 0; b < 4; ++b) {
      float hbl = 0.f;
#pragma unroll
      for (int p = 0; p < 12; ++p) {
        const float4* A = (const float4*)&accTw[b * 96 + p * 8];
        float4 A0 = A[0], A1 = A[1];
        float za = bz + A0.x * wz[0] + A0.y * wz[1] + A0.z * wz[2] + A0.w * wz[3]
                      + A1.x * wz[4] + A1.y * wz[5] + A1.z * wz[6] + A1.w * wz[7];
        float ta = bh + A0.x * wh[0] + A0.y * wh[1] + A0.z * wh[2] + A0.w * wh[3]
                      + A1.x * wh[4] + A1.y * wh[5] + A1.z * wh[6] + A1.w * wh[7];
        float ea2 = ex2(za);
        float eh = ex2(fminf(ta, 115.0f));
        float num = eh - 1.0f;
        float den = (1.0f + ea2) * (1.0f + eh);
        hbl += prv[p] * (num * __builtin_amdgcn_rcpf(den));
      }
      hww[b * 68 + lane] = fmaxf(hbl, 0.f);
    }
  }
  __builtin_amdgcn_wave_barrier();

  if (lane < 48) {
    const float* hww = &hw[w * 272];
    int b = lane / 12, p = lane % 12;
    float o = sow[816 + p];
#pragma unroll
    for (int kq = 0; kq < 16; ++kq) {
      float4 hv = *(const float4*)&hww[b * 68 + 4 * kq];
      float4 wv = *(const float4*)&sow[p * 68 + 4 * kq];
      o += hv.x * wv.x + hv.y * wv.y + hv.z * wv.z + hv.w * wv.w;
    }
    int oi = (b * NN + n) * 12 + p;
    if (isbf) ((unsigned short*)out)[oi] = f2b(o);
    else      ((float*)out)[oi] = o;
  }
}

extern "C" void kernel_launch(void* const* d_in, const int* in_sizes, int n_in,
                              void* d_out, int out_size, void* d_ws, size_t ws_size,
                              hipStream_t stream) {
  const void* x   = d_in[0];
  const void* ei  = d_in[1];
  const void* ea  = d_in[2];
  const void* czw = d_in[3];
  const void* czb = d_in[4];
  // d_in[5], d_in[6]: conv_r_* — dead (H0 = 0)
  const void* chw = d_in[7];
  const void* chb = d_in[8];
  const void* lzw = d_in[9];
  const void* lzb = d_in[10];
  // d_in[11], d_in[12]: lin_r_* — dead
  const void* lhw = d_in[13];
  const void* lhb = d_in[14];
  const void* att = d_in[15];
  const void* ow  = d_in[16];
  const void* ob  = d_in[17];

  // workspace ~5.4 MB
  char* ws = (char*)d_ws;
  float* consts  = (float*)(ws + 256);                             // 1992 f32
  unsigned long long* degcnt = (unsigned long long*)(ws + 8448);   // 160,000 B
  int*   ovf_cnt = (int*)  (ws + 168448);
  int*   wq      = (int*)  (ws + 168512);                          // node work queue
  int*   ovf_dst = (int*)  (ws + 168704);                          // 32768 B
  unsigned int* ovf_pack = (unsigned int*)(ws + 201472);           // 32768 B
  unsigned int* slab     = (unsigned int*)(ws + 234240);           // 5,120,000 B

  // zero degcnt + ovf_cnt + work queue (one DMA fill; covers [8448, 168576))
  hipMemsetAsync(ws + 8448, 0, 160128, stream);

  static int mode = 0;   // 0 = try cooperative fused; 1 = fallback split kernels
  if (mode == 0) {
    void* outp = d_out;
    void* args[22] = {
        (void*)&x,  (void*)&ei,  (void*)&ea,
        (void*)&czw, (void*)&czb, (void*)&chw, (void*)&chb,
        (void*)&lzw, (void*)&lzb, (void*)&lhw, (void*)&lhb,
        (void*)&att, (void*)&ow,  (void*)&ob,
        (void*)&degcnt, (void*)&slab, (void*)&ovf_cnt, (void*)&ovf_dst,
        (void*)&ovf_pack, (void*)&consts, (void*)&wq, (void*)&outp};
    hipError_t err = hipLaunchCooperativeKernel(k_fused, dim3(GRID), dim3(256),
                                                args, 0u, stream);
    if (err == hipSuccess) return;
    (void)hipGetLastError();   // clear sticky error, fall through to split path
    mode = 1;
  }

  k_append<<<dim3(EBLK + 1), dim3(256), 0, stream>>>(ei, ea, degcnt, slab,
                                                     ovf_cnt, ovf_dst, ovf_pack,
                                                     consts,
                                                     czw, czb, chw, chb,
                                                     lzw, lzb, lhw, lhb,
                                                     att, ow, ob);
  k_node<<<dim3(NN / 4), dim3(256), 0, stream>>>(x, ea, degcnt, slab,
                                                 ovf_cnt, ovf_dst, ovf_pack,
                                                 consts, d_out);
}

// Round 4
// 229.204 us; speedup vs baseline: 1.0144x; 1.0033x over previous
//
#include <hip/hip_runtime.h>

#define NN 20000
#define EE 320000
#define CAP 64           // slab slots per node (in-degree ~ Poisson(16))
#define SVC 72           // per-wave edge capacity (CAP + ovf slack + self)
#define OVCAP 8192
#define EBLK 1250        // edge blocks: 1 edge/thread, 1250*256 == 320000

// consts layout (float offsets)
#define WZ_O 0
#define BZ_O 512
#define WH_O 576
#define BH_O 1088
#define OWT_O 1152       // transposed+padded out weights: [p][68] (k<64 valid)
#define OB_O 1968
#define PR_O 1980

#define LOG2E 1.44269504088896340736f

typedef float v2f __attribute__((ext_vector_type(2)));

__device__ __forceinline__ v2f mk2(float a, float b) { v2f t; t.x = a; t.y = b; return t; }
__device__ __forceinline__ v2f pkfma(v2f a, v2f b, v2f c) {
  v2f d;
  asm("v_pk_fma_f32 %0, %1, %2, %3" : "=v"(d) : "v"(a), "v"(b), "v"(c));
  return d;
}
__device__ __forceinline__ v2f pkmul(v2f a, v2f b) {
  v2f d;
  asm("v_pk_mul_f32 %0, %1, %2" : "=v"(d) : "v"(a), "v"(b));
  return d;
}

__device__ __forceinline__ float b2f(unsigned short h) {
  union { unsigned int u; float f; } v; v.u = ((unsigned int)h) << 16; return v.f;
}
__device__ __forceinline__ unsigned short f2b(float f) {
  union { unsigned int u; float f; } v; v.f = f;
  unsigned int u = v.u;
  unsigned int r = (u + 0x7fffu + ((u >> 16) & 1u)) >> 16;  // RNE
  return (unsigned short)r;
}
__device__ __forceinline__ float ldw(const void* p, int i, int isbf) {
  return isbf ? b2f(((const unsigned short*)p)[i]) : ((const float*)p)[i];
}
__device__ __forceinline__ float degf(unsigned long long dc) {
  return (float)(unsigned int)dc * (1.0f / 1048576.0f);
}
__device__ __forceinline__ float ex2(float x) {
#if __has_builtin(__builtin_amdgcn_exp2f)
  return __builtin_amdgcn_exp2f(x);
#else
  return __exp2f(x);
#endif
}
__device__ __forceinline__ v2f bpk(unsigned int u) {   // packed bf16 word -> 2 floats
  union { unsigned int i; float f; } lo, hi;
  lo.i = u << 16; hi.i = u & 0xffff0000u;
  return mk2(lo.f, hi.f);
}

struct __align__(4) U3 { unsigned int x, y, z; };   // 12B dwordx3 load

// 1) k_append: blocks 0..EBLK-1, 1 edge/thread (max TLP for the atomic scatter).
//    One packed 64-bit atomic per edge -> slot index in hi32 + fixed-point
//    weighted degree in lo32; degcnt pre-zeroed by a 160 KB memset.
//    Block EBLK (concurrent): fused-weight prep, pre-scaled by log2e so k_node
//    uses bare v_exp_f32.
__global__ void __launch_bounds__(256) k_append(
    const void* __restrict__ ei, const void* __restrict__ ea,
    unsigned long long* __restrict__ degcnt,
    unsigned int* __restrict__ slab,
    int* __restrict__ ovf_cnt, int* __restrict__ ovf_dst,
    unsigned int* __restrict__ ovf_pack, float* __restrict__ consts,
    const void* czw, const void* czb, const void* chw, const void* chb,
    const void* lzw, const void* lzb, const void* lhw, const void* lhb,
    const void* att, const void* ow, const void* ob) {
  __shared__ int sfl[2];
  const int tid = threadIdx.x;
  if (tid < 64) {
    // edge_attr in (0,1): packed-bf16 words have sign bits 15/31==0; f32 random bit15
    unsigned long long b1 = __ballot((((const unsigned int*)ea)[tid] >> 15) & 1u);
    // edge_index < 20000: int64 arrays have all odd 32-bit words == 0
    unsigned long long b2 = __ballot(((const unsigned int*)ei)[2 * tid + 1] != 0u);
    if (tid == 0) {
      sfl[0] = (b1 == 0ull) ? 1 : 0;   // floats are bf16
      sfl[1] = (b2 == 0ull) ? 1 : 0;   // indices are int64
    }
  }
  __syncthreads();
  const int isbf = sfl[0], is64 = sfl[1];

  if (blockIdx.x == EBLK) {
    // ---- weight prep block (concurrent with edge blocks) ----
    for (int idx = tid; idx < 512; idx += 256) {
      int f = idx >> 6, k = idx & 63;
      float sz = 0.f, sh = 0.f;
      for (int h = 0; h < 64; ++h) {
        sz += ldw(czw, f * 64 + h, isbf) * ldw(lzw, h * 64 + k, isbf);
        sh += ldw(chw, f * 64 + h, isbf) * ldw(lhw, h * 64 + k, isbf);
      }
      consts[WZ_O + idx] = sz * LOG2E;
      consts[WH_O + idx] = sh * (2.0f * LOG2E);
    }
    for (int idx = tid; idx < 64; idx += 256) {
      float sz = ldw(lzb, idx, isbf), sh = ldw(lhb, idx, isbf);
      for (int h = 0; h < 64; ++h) {
        sz += ldw(czb, h, isbf) * ldw(lzw, h * 64 + idx, isbf);
        sh += ldw(chb, h, isbf) * ldw(lhw, h * 64 + idx, isbf);
      }
      consts[BZ_O + idx] = sz * LOG2E;
      consts[BH_O + idx] = sh * (2.0f * LOG2E);
    }
    for (int idx = tid; idx < 816; idx += 256) {    // out weights [p][k], rows padded to 68
      int p = idx / 68, kk = idx % 68;
      consts[OWT_O + idx] = (kk < 64) ? ldw(ow, kk * 12 + p, isbf) : 0.f;
    }
    if (tid < 12) consts[OB_O + tid] = ldw(ob, tid, isbf);
    if (tid == 0) {
      float a[12]; float m = -1e30f;
      for (int p = 0; p < 12; ++p) { a[p] = ldw(att, p, isbf); m = fmaxf(m, a[p]); }
      float ssum = 0.f;
      for (int p = 0; p < 12; ++p) { a[p] = __expf(a[p] - m); ssum += a[p]; }
      for (int p = 0; p < 12; ++p) consts[PR_O + p] = a[p] / ssum;
    }
    return;
  }

  // ---- edge blocks: 1 edge per thread ----
  const int e = blockIdx.x * 256 + tid;
  if (e < EE) {
    int r, c;
    if (is64) {
      r = (int)((const unsigned int*)ei)[2 * e];
      c = (int)((const unsigned int*)ei)[2 * (EE + e)];
    } else {
      r = ((const int*)ei)[e];
      c = ((const int*)ei)[EE + e];
    }
    unsigned short wb;
    float wv;
    if (isbf) { wb = ((const unsigned short*)ea)[e]; wv = b2f(wb); }
    else      { wv = ((const float*)ea)[e]; wb = f2b(wv); }
    unsigned long long pk = (1ull << 32) |
        (unsigned long long)(unsigned int)__float2int_rn(wv * 1048576.0f);
    unsigned long long old = atomicAdd(&degcnt[c], pk);
    int pos = (int)(old >> 32);
    unsigned int packed = ((unsigned int)wb << 16) | (unsigned int)r;
    if (pos < CAP) {
      slab[c * CAP + pos] = packed;
    } else {
      int oi = atomicAdd(ovf_cnt, 1);
      if (oi < OVCAP) { ovf_dst[oi] = c; ovf_pack[oi] = packed; }
    }
  }
}

#define ACC6P(u, vv)                              \
  { aa0 = pkfma(bpk((u).x), vv, aa0);             \
    aa1 = pkfma(bpk((u).y), vv, aa1);             \
    aa2 = pkfma(bpk((u).z), vv, aa2); }

// 2) barrier-free wave-per-node (proven R1 structure) with v_pk_fma_f32 in
//    gather, gates, and out-projection. 4 waves/block, wave owns one node.
__global__ void __launch_bounds__(256) k_node(
    const void* __restrict__ x, const void* __restrict__ ea,
    const unsigned long long* __restrict__ degcnt,
    const unsigned int* __restrict__ slab,
    const int* __restrict__ ovf_cnt, const int* __restrict__ ovf_dst,
    const unsigned int* __restrict__ ovf_pack,
    const float* __restrict__ consts,
    void* __restrict__ out) {
  __shared__ __align__(16) float sow[840];        // owT 816 | ob 12 | pr 12
  __shared__ __align__(16) int2  sv[4 * SVC];     // per-wave edges {elem-off, v-bits}
  __shared__ __align__(16) float accT[4 * 384];   // per-wave [b][p][f]
  __shared__ __align__(16) float hw[4 * 272];     // per-wave [b][68]
  __shared__ int swcnt[4];
  __shared__ int sfl[1];

  const int tid  = threadIdx.x;
  const int w    = tid >> 6;
  const int lane = tid & 63;
  const int n    = blockIdx.x * 4 + w;

  if (tid < 64) {
    unsigned long long b1 = __ballot((((const unsigned int*)ea)[tid] >> 15) & 1u);
    if (tid == 0) sfl[0] = (b1 == 0ull) ? 1 : 0;
  }
  for (int i = tid; i < 840; i += 256) sow[i] = consts[OWT_O + i];
  v2f wzp[4], whp[4];
#pragma unroll
  for (int j = 0; j < 4; ++j) {
    wzp[j] = mk2(consts[WZ_O + (2 * j) * 64 + lane], consts[WZ_O + (2 * j + 1) * 64 + lane]);
    whp[j] = mk2(consts[WH_O + (2 * j) * 64 + lane], consts[WH_O + (2 * j + 1) * 64 + lane]);
  }
  const float bz = consts[BZ_O + lane], bh = consts[BH_O + lane];
  __syncthreads();   // sow + sfl ready (only block barrier)
  const int isbf = sfl[0];

  // --- stage this wave's edges into its LDS slab (dest-side dn folded into v) ---
  unsigned long long dcn = degcnt[n];
  int cnt = (int)(dcn >> 32);
  int base = cnt < CAP ? cnt : CAP;
  const float dn = rsqrtf(degf(dcn) + 1.0f);
  int2* svw = &sv[w * SVC];
  if (lane == 0) swcnt[w] = base;
  if (lane < base) {
    unsigned int pk = slab[n * CAP + lane];
    int s = (int)(pk & 0xffffu);
    float v = b2f((unsigned short)(pk >> 16)) * rsqrtf(degf(degcnt[s]) + 1.0f) * dn;
    svw[lane] = make_int2(s * 96, __float_as_int(v));
  }
  int m0 = base;
  {
    int ov = ovf_cnt[0];                 // expected 0
    if (ov > 0) {
      if (ov > OVCAP) ov = OVCAP;
      for (int i = lane; i < ov; i += 64) {
        if (ovf_dst[i] == n) {
          int idx = atomicAdd(&swcnt[w], 1);
          if (idx < SVC - 1) {
            unsigned int pk = ovf_pack[i];
            int s = (int)(pk & 0xffffu);
            float v = b2f((unsigned short)(pk >> 16)) *
                      rsqrtf(degf(degcnt[s]) + 1.0f) * dn;
            svw[idx] = make_int2(s * 96, __float_as_int(v));
          }
        }
      }
      __builtin_amdgcn_wave_barrier();
      m0 = swcnt[w];
      if (m0 > SVC - 1) m0 = SVC - 1;
    }
  }
  if (lane == 0) svw[m0] = make_int2(n * 96, __float_as_int(dn * dn));  // self loop
  const int m1 = m0 + 1;
  __builtin_amdgcn_wave_barrier();

  // --- gather: all 64 lanes, lane owns 6 payload elems; packed-f32 FMAs ---
  v2f aa0 = mk2(0.f, 0.f), aa1 = mk2(0.f, 0.f), aa2 = mk2(0.f, 0.f);
  {
    const int i15 = lane & 15;
    const long xbase = (long)(lane >> 4) * (NN * 96) + 6 * i15;
    if (isbf) {
      const unsigned short* xr = (const unsigned short*)x + xbase;
      int j = 0;
      for (; j + 1 < m1; j += 2) {
        int2 e0 = svw[j], e1 = svw[j + 1];
        U3 u0 = *(const U3*)(xr + e0.x);
        U3 u1 = *(const U3*)(xr + e1.x);
        v2f vv0 = mk2(__int_as_float(e0.y), __int_as_float(e0.y));
        v2f vv1 = mk2(__int_as_float(e1.y), __int_as_float(e1.y));
        ACC6P(u0, vv0); ACC6P(u1, vv1);
      }
      if (j < m1) {
        int2 e0 = svw[j];
        U3 u0 = *(const U3*)(xr + e0.x);
        v2f vv0 = mk2(__int_as_float(e0.y), __int_as_float(e0.y));
        ACC6P(u0, vv0);
      }
    } else {
      const float* xf = (const float*)x + xbase;
      int j = 0;
      for (; j + 1 < m1; j += 2) {
        int2 e0 = svw[j], e1 = svw[j + 1];
        const v2f* p0 = (const v2f*)(xf + e0.x);
        const v2f* p1 = (const v2f*)(xf + e1.x);
        v2f u00 = p0[0], u01 = p0[1], u02 = p0[2];
        v2f u10 = p1[0], u11 = p1[1], u12 = p1[2];
        v2f vv0 = mk2(__int_as_float(e0.y), __int_as_float(e0.y));
        v2f vv1 = mk2(__int_as_float(e1.y), __int_as_float(e1.y));
        aa0 = pkfma(u00, vv0, aa0); aa1 = pkfma(u01, vv0, aa1); aa2 = pkfma(u02, vv0, aa2);
        aa0 = pkfma(u10, vv1, aa0); aa1 = pkfma(u11, vv1, aa1); aa2 = pkfma(u12, vv1, aa2);
      }
      if (j < m1) {
        int2 e0 = svw[j];
        const v2f* p0 = (const v2f*)(xf + e0.x);
        v2f vv0 = mk2(__int_as_float(e0.y), __int_as_float(e0.y));
        aa0 = pkfma(p0[0], vv0, aa0); aa1 = pkfma(p0[1], vv0, aa1); aa2 = pkfma(p0[2], vv0, aa2);
      }
    }
    // divmod-free scatter-transpose into accT[b][p][f]:
    // oc = 6*i15 -> f = i15>>1 (fixed), p = 6*(i15&1)+t (t<6, never wraps)
    float* aw = &accT[w * 384 + (lane >> 4) * 96 + (i15 & 1) * 48 + (i15 >> 1)];
    aw[0]  = aa0.x; aw[8]  = aa0.y;
    aw[16] = aa1.x; aw[24] = aa1.y;
    aw[32] = aa2.x; aw[40] = aa2.y;
  }
  __builtin_amdgcn_wave_barrier();

  // --- gates: lane = hidden k; packed FMAs; weights pre-scaled by log2e -> bare exp2 ---
  {
    const float* accTw = &accT[w * 384];
    float* hww = &hw[w * 272];
    float prv[12];
#pragma unroll
    for (int p = 0; p < 12; ++p) prv[p] = sow[828 + p];
#pragma unroll
    for (int b = 0; b < 4; ++b) {
      float hbl = 0.f;
#pragma unroll
      for (int p = 0; p < 12; ++p) {
        const float4* A = (const float4*)&accTw[b * 96 + p * 8];
        float4 A0 = A[0], A1 = A[1];
        v2f zv = pkmul(mk2(A0.x, A0.y), wzp[0]);
        zv = pkfma(mk2(A0.z, A0.w), wzp[1], zv);
        zv = pkfma(mk2(A1.x, A1.y), wzp[2], zv);
        zv = pkfma(mk2(A1.z, A1.w), wzp[3], zv);
        v2f tv = pkmul(mk2(A0.x, A0.y), whp[0]);
        tv = pkfma(mk2(A0.z, A0.w), whp[1], tv);
        tv = pkfma(mk2(A1.x, A1.y), whp[2], tv);
        tv = pkfma(mk2(A1.z, A1.w), whp[3], tv);
        float za = zv.x + zv.y + bz;
        float ta = tv.x + tv.y + bh;
        // (1 - sigmoid(z)) * tanh(t) = (eh-1)/((1+ea)(1+eh)), ea=2^za, eh=2^ta
        float ea2 = ex2(za);
        float eh = ex2(fminf(ta, 115.0f));
        float num = eh - 1.0f;
        float den = (1.0f + ea2) * (1.0f + eh);
        hbl += prv[p] * (num * __builtin_amdgcn_rcpf(den));
      }
      hww[b * 68 + lane] = fmaxf(hbl, 0.f);   // relu
    }
  }
  __builtin_amdgcn_wave_barrier();

  // --- out projection: lane t<48 -> (b,p); b128 reads + packed FMAs ---
  if (lane < 48) {
    const float* hww = &hw[w * 272];
    int b = lane / 12, p = lane % 12;
    v2f acc2 = mk2(0.f, 0.f);
#pragma unroll
    for (int kq = 0; kq < 16; ++kq) {
      float4 hv = *(const float4*)&hww[b * 68 + 4 * kq];
      float4 wv = *(const float4*)&sow[p * 68 + 4 * kq];
      acc2 = pkfma(mk2(hv.x, hv.y), mk2(wv.x, wv.y), acc2);
      acc2 = pkfma(mk2(hv.z, hv.w), mk2(wv.z, wv.w), acc2);
    }
    float o = acc2.x + acc2.y + sow[816 + p];
    int oi = (b * NN + n) * 12 + p;
    if (isbf) ((unsigned short*)out)[oi] = f2b(o);
    else      ((float*)out)[oi] = o;
  }
}

extern "C" void kernel_launch(void* const* d_in, const int* in_sizes, int n_in,
                              void* d_out, int out_size, void* d_ws, size_t ws_size,
                              hipStream_t stream) {
  const void* x   = d_in[0];
  const void* ei  = d_in[1];
  const void* ea  = d_in[2];
  const void* czw = d_in[3];
  const void* czb = d_in[4];
  // d_in[5], d_in[6]: conv_r_* — dead (H0 = 0)
  const void* chw = d_in[7];
  const void* chb = d_in[8];
  const void* lzw = d_in[9];
  const void* lzb = d_in[10];
  // d_in[11], d_in[12]: lin_r_* — dead
  const void* lhw = d_in[13];
  const void* lhb = d_in[14];
  const void* att = d_in[15];
  const void* ow  = d_in[16];
  const void* ob  = d_in[17];

  // workspace ~5.4 MB
  char* ws = (char*)d_ws;
  float* consts  = (float*)(ws + 256);                             // 1992 f32
  unsigned long long* degcnt = (unsigned long long*)(ws + 8448);   // 160,000 B
  int*   ovf_cnt = (int*)  (ws + 168448);
  int*   ovf_dst = (int*)  (ws + 168704);                          // 32768 B
  unsigned int* ovf_pack = (unsigned int*)(ws + 201472);           // 32768 B
  unsigned int* slab     = (unsigned int*)(ws + 234240);           // 5,120,000 B

  // zero degcnt + ovf_cnt (one DMA fill)
  hipMemsetAsync(ws + 8448, 0, 160064, stream);
  k_append<<<dim3(EBLK + 1), dim3(256), 0, stream>>>(ei, ea, degcnt, slab,
                                                     ovf_cnt, ovf_dst, ovf_pack,
                                                     consts,
                                                     czw, czb, chw, chb,
                                                     lzw, lzb, lhw, lhb,
                                                     att, ow, ob);
  k_node<<<dim3(NN / 4), dim3(256), 0, stream>>>(x, ea, degcnt, slab,
                                                 ovf_cnt, ovf_dst, ovf_pack,
                                                 consts, d_out);
}